// Round 1
// baseline (6455.127 us; speedup 1.0000x reference)
//
#include <hip/hip_runtime.h>
#include <math.h>

#define NB     16384
#define NTOT   427
#define NROI   30
#define TDIM   10
#define HDIM   64
#define FCD    32
#define NHD    256
#define NROIF  300
#define NOTHER 127
#define ACTD   31
#define NSEQ   (NB*NROI)
#define COMB   1216

__device__ __forceinline__ float sigmf(float v) { return 1.0f / (1.0f + __expf(-v)); }
__device__ __forceinline__ float tanh_fast(float v) {
    float e = __expf(2.0f * v);
    return 1.0f - 2.0f / (e + 1.0f);
}

// ---------------------------------------------------------------------------
// MLP layer: out[M=16384][256] = relu(in[M][K] @ W^T + b)
// 64 rows x 256 cols per block, 256 threads, 8x8 register tile / thread.
// ---------------------------------------------------------------------------
template<int KDIM>
__global__ __launch_bounds__(256) void mlp_kernel(
    const float* __restrict__ in, int ld_in,
    const float* __restrict__ W, const float* __restrict__ bias,
    float* __restrict__ out, int ld_out)
{
    __shared__ float in_t[32][68];   // [k][m], padded: 16B-aligned rows, 2-way max
    __shared__ float w_t[32][260];   // [k][j]

    const int tid = threadIdx.x;
    const int m0  = blockIdx.x * 64;
    const int a   = tid & 7;    // row group: rows m0+8a .. m0+8a+7
    const int bc  = tid >> 3;   // col group: cols 8bc .. 8bc+7

    float acc[8][8];
    #pragma unroll
    for (int i = 0; i < 8; i++)
        #pragma unroll
        for (int jj = 0; jj < 8; jj++) acc[i][jj] = 0.0f;

    for (int k0 = 0; k0 < KDIM; k0 += 32) {
        __syncthreads();
        // stage input tile (transposed): coalesced global read
        #pragma unroll
        for (int e = 0; e < 8; e++) {
            int idx = tid + e * 256;          // 0..2047
            int k = idx & 31, m = idx >> 5;   // k 0..31, m 0..63
            float v = 0.0f;
            if ((KDIM % 32 == 0) || (k0 + k < KDIM))
                v = in[(size_t)(m0 + m) * ld_in + k0 + k];
            in_t[k][m] = v;
        }
        // stage W tile (transposed): thread j = tid reads its row chunk
        {
            const int j = tid;
            #pragma unroll
            for (int e = 0; e < 8; e++) {
                #pragma unroll
                for (int qq = 0; qq < 4; qq++) {
                    int k = e * 4 + qq;
                    float v = 0.0f;
                    if ((KDIM % 32 == 0) || (k0 + k < KDIM))
                        v = W[(size_t)j * KDIM + k0 + k];
                    w_t[k][j] = v;
                }
            }
        }
        __syncthreads();
        #pragma unroll 4
        for (int k = 0; k < 32; k++) {
            float av[8], wv[8];
            #pragma unroll
            for (int i = 0; i < 8; i++)  av[i] = in_t[k][a * 8 + i];
            #pragma unroll
            for (int jj = 0; jj < 8; jj++) wv[jj] = w_t[k][bc * 8 + jj];
            #pragma unroll
            for (int i = 0; i < 8; i++)
                #pragma unroll
                for (int jj = 0; jj < 8; jj++)
                    acc[i][jj] = __fmaf_rn(av[i], wv[jj], acc[i][jj]);
        }
    }

    float bv[8];
    #pragma unroll
    for (int jj = 0; jj < 8; jj++) bv[jj] = bias[bc * 8 + jj];
    #pragma unroll
    for (int i = 0; i < 8; i++) {
        float* orow = out + (size_t)(m0 + a * 8 + i) * ld_out + bc * 8;
        #pragma unroll
        for (int jj = 0; jj < 8; jj++) {
            float v = acc[i][jj] + bv[jj];
            orow[jj] = v > 0.0f ? v : 0.0f;
        }
    }
}

// ---------------------------------------------------------------------------
// Fused bidirectional LSTM + FC per 64 sequences.
// 256 threads: thread = (a = tid&7 -> seqs 8a..8a+7, bc = tid>>3 -> units 2bc,2bc+1).
// Gate-interleaved W layout: j' = unit*4 + gate, gates i,f,g,o.
// H state in LDS as Ht[k][s]; c state in registers.
// ---------------------------------------------------------------------------
__global__ __launch_bounds__(256) void lstm_fc_kernel(
    const float* __restrict__ x,
    const float* __restrict__ Wih_f, const float* __restrict__ Whh_f,
    const float* __restrict__ bih_f, const float* __restrict__ bhh_f,
    const float* __restrict__ Wih_b, const float* __restrict__ Whh_b,
    const float* __restrict__ bih_b, const float* __restrict__ bhh_b,
    const float* __restrict__ Wfc, const float* __restrict__ bfc,
    float* __restrict__ combined)
{
    __shared__ float Wt[64][260];    // [k][j'] gate-interleaved W_hh^T  (66.6 KB)
    __shared__ float Htf[64][68];    // forward  h, [unit][seq]          (17.4 KB)
    __shared__ float Htb[64][68];    // backward h                        (17.4 KB)
    __shared__ float Xs[64][TDIM];   // per-seq scalar inputs
    __shared__ int   lens_i[64];
    __shared__ float wih_s[256];     // gate-interleaved W_ih
    __shared__ float bb_s[256];      // gate-interleaved b_ih+b_hh
    __shared__ float wfc_s[FCD][128];
    __shared__ float bfc_s[FCD];

    const int tid    = threadIdx.x;
    const int s0base = blockIdx.x * 64;
    const int a      = tid & 7;
    const int bc     = tid >> 3;
    const int s_lo   = a * 8;

    // stage X tile and FC weights
    for (int idx = tid; idx < 64 * TDIM; idx += 256) {
        int s = idx / TDIM, t = idx - s * TDIM;
        int gs = s0base + s;
        int row = gs / NROI, r = gs - row * NROI;
        Xs[s][t] = x[(size_t)row * NTOT + r * TDIM + t];
    }
    for (int idx = tid; idx < FCD * 128; idx += 256)
        wfc_s[idx >> 7][idx & 127] = Wfc[idx];
    if (tid < FCD) bfc_s[tid] = bfc[tid];
    __syncthreads();
    if (tid < 64) {
        int c = 0;
        #pragma unroll
        for (int t = 0; t < TDIM; t++) c += (Xs[tid][t] != 0.0f) ? 1 : 0;
        lens_i[tid] = c;
    }
    __syncthreads();
    int len8[8];
    #pragma unroll
    for (int i = 0; i < 8; i++) len8[i] = lens_i[s_lo + i];

    for (int dir = 0; dir < 2; dir++) {
        const float* Whh  = dir ? Whh_b : Whh_f;
        const float* Wih  = dir ? Wih_b : Wih_f;
        const float* bihp = dir ? bih_b : bih_f;
        const float* bhhp = dir ? bhh_b : bhh_f;
        float (*Ht)[68] = dir ? Htb : Htf;

        __syncthreads();
        // stage gate-interleaved transposed W_hh (coalesced global read)
        for (int e = 0; e < 64; e++) {
            int l = tid + e * 256;                 // 0..16383
            int j = l >> 6, k = l & 63;
            int jp = ((j & 63) << 2) | (j >> 6);   // unit*4 + gate
            Wt[k][jp] = Whh[l];
        }
        {
            const int j = tid;
            const int jp = ((j & 63) << 2) | (j >> 6);
            wih_s[jp] = Wih[j];
            bb_s[jp]  = bihp[j] + bhhp[j];
        }
        for (int idx = tid; idx < 64 * 68; idx += 256) (&Ht[0][0])[idx] = 0.0f;
        float cst[2][8];
        #pragma unroll
        for (int u = 0; u < 2; u++)
            #pragma unroll
            for (int i = 0; i < 8; i++) cst[u][i] = 0.0f;
        __syncthreads();

        for (int step = 0; step < TDIM; step++) {
            const int t = dir ? (TDIM - 1 - step) : step;

            float acc[8][8];
            #pragma unroll
            for (int i = 0; i < 8; i++)
                #pragma unroll
                for (int jj = 0; jj < 8; jj++) acc[i][jj] = 0.0f;

            #pragma unroll 4
            for (int k = 0; k < HDIM; k++) {
                float av[8], wv[8];
                #pragma unroll
                for (int i = 0; i < 8; i++)  av[i] = Ht[k][s_lo + i];
                #pragma unroll
                for (int jj = 0; jj < 8; jj++) wv[jj] = Wt[k][bc * 8 + jj];
                #pragma unroll
                for (int i = 0; i < 8; i++)
                    #pragma unroll
                    for (int jj = 0; jj < 8; jj++)
                        acc[i][jj] = __fmaf_rn(av[i], wv[jj], acc[i][jj]);
            }

            float hst[2][8];
            #pragma unroll
            for (int i = 0; i < 8; i++) {
                const int s   = s_lo + i;
                const float xv = Xs[s][t];
                const bool m  = (t < len8[i]);
                #pragma unroll
                for (int u = 0; u < 2; u++) {
                    const int jb = bc * 8 + u * 4;
                    float gi = acc[i][u*4+0] + xv * wih_s[jb+0] + bb_s[jb+0];
                    float gf = acc[i][u*4+1] + xv * wih_s[jb+1] + bb_s[jb+1];
                    float gg = acc[i][u*4+2] + xv * wih_s[jb+2] + bb_s[jb+2];
                    float go = acc[i][u*4+3] + xv * wih_s[jb+3] + bb_s[jb+3];
                    float cn = sigmf(gf) * cst[u][i] + sigmf(gi) * tanh_fast(gg);
                    float hn = sigmf(go) * tanh_fast(cn);
                    float hold = Ht[bc * 2 + u][s];      // pre-barrier read of old h
                    if (m) cst[u][i] = cn;
                    hst[u][i] = m ? hn : hold;
                }
            }
            __syncthreads();
            #pragma unroll
            for (int u = 0; u < 2; u++) {
                const int unit = bc * 2 + u;
                float4* dst = (float4*)&Ht[unit][s_lo];
                dst[0] = make_float4(hst[u][0], hst[u][1], hst[u][2], hst[u][3]);
                dst[1] = make_float4(hst[u][4], hst[u][5], hst[u][6], hst[u][7]);
            }
            __syncthreads();
        }
    }

    // FC epilogue: roi_out[s][f] = relu(b_fc[f] + hf . Wfc[f][0:64] + hb . Wfc[f][64:128])
    {
        const int s  = tid & 63;
        const int fg = tid >> 6;   // 0..3 -> 8 f's each
        float facc[8];
        #pragma unroll
        for (int ff = 0; ff < 8; ff++) facc[ff] = bfc_s[fg * 8 + ff];
        for (int u = 0; u < HDIM; u++) {
            float hf = Htf[u][s];
            float hb = Htb[u][s];
            #pragma unroll
            for (int ff = 0; ff < 8; ff++)
                facc[ff] += hf * wfc_s[fg*8+ff][u] + hb * wfc_s[fg*8+ff][64 + u];
        }
        const int gs  = s0base + s;
        const int row = gs / NROI, r = gs - row * NROI;
        float* orow = combined + (size_t)row * COMB + r * FCD + fg * 8;
        #pragma unroll
        for (int ff = 0; ff < 8; ff++) {
            float v = facc[ff];
            orow[ff] = v > 0.0f ? v : 0.0f;
        }
    }
}

// ---------------------------------------------------------------------------
// Output projection: q[row][j] = b_out[j] + combined[row] . W_out[j]
// block = (31, 8): 8 rows x 31 outputs, float4 dot over 1216.
// ---------------------------------------------------------------------------
__global__ void qout_kernel(const float* __restrict__ combined,
                            const float* __restrict__ Wout,
                            const float* __restrict__ bout,
                            float* __restrict__ q)
{
    const int j   = threadIdx.x;              // 0..30
    const int r   = threadIdx.y;              // 0..7
    const int row = blockIdx.x * 8 + r;
    const float4* crow = (const float4*)(combined + (size_t)row * COMB);
    const float4* wrow = (const float4*)(Wout + (size_t)j * COMB);
    float acc = bout[j];
    #pragma unroll 4
    for (int k4 = 0; k4 < COMB / 4; k4++) {
        float4 c4 = crow[k4];
        float4 w4 = wrow[k4];
        acc += c4.x * w4.x + c4.y * w4.y + c4.z * w4.z + c4.w * w4.w;
    }
    q[(size_t)row * ACTD + j] = acc;
}

// ---------------------------------------------------------------------------
extern "C" void kernel_launch(void* const* d_in, const int* in_sizes, int n_in,
                              void* d_out, int out_size, void* d_ws, size_t ws_size,
                              hipStream_t stream)
{
    (void)in_sizes; (void)n_in; (void)out_size;
    const float* x     = (const float*)d_in[0];
    const float* Wih_f = (const float*)d_in[1];
    const float* Whh_f = (const float*)d_in[2];
    const float* bih_f = (const float*)d_in[3];
    const float* bhh_f = (const float*)d_in[4];
    const float* Wih_b = (const float*)d_in[5];
    const float* Whh_b = (const float*)d_in[6];
    const float* bih_b = (const float*)d_in[7];
    const float* bhh_b = (const float*)d_in[8];
    const float* Wfc   = (const float*)d_in[9];
    const float* bfc   = (const float*)d_in[10];
    const float* W1    = (const float*)d_in[11];
    const float* b1    = (const float*)d_in[12];
    const float* W2    = (const float*)d_in[13];
    const float* b2    = (const float*)d_in[14];
    const float* W3    = (const float*)d_in[15];
    const float* b3    = (const float*)d_in[16];
    const float* Wout  = (const float*)d_in[17];
    const float* bout  = (const float*)d_in[18];
    float* q        = (float*)d_out;
    float* combined = (float*)d_ws;   // 16384 x 1216 f32 = 79.7 MB

    if (ws_size < (size_t)NB * COMB * sizeof(float)) return;

    // MLP: h1 -> combined[:,0:256], h2 -> combined[:,256:512], out -> combined[:,960:1216].
    // lstm_fc later overwrites cols [0,960) with roi_out (stream-ordered, safe).
    mlp_kernel<NOTHER><<<NB / 64, 256, 0, stream>>>(x + NROIF, NTOT, W1, b1, combined, COMB);
    mlp_kernel<NHD><<<NB / 64, 256, 0, stream>>>(combined, COMB, W2, b2, combined + 256, COMB);
    mlp_kernel<NHD><<<NB / 64, 256, 0, stream>>>(combined + 256, COMB, W3, b3, combined + 960, COMB);

    lstm_fc_kernel<<<NSEQ / 64, 256, 0, stream>>>(x, Wih_f, Whh_f, bih_f, bhh_f,
                                                  Wih_b, Whh_b, bih_b, bhh_b,
                                                  Wfc, bfc, combined);

    qout_kernel<<<NB / 8, dim3(31, 8), 0, stream>>>(combined, Wout, bout, q);
}

// Round 2
// 3525.631 us; speedup vs baseline: 1.8309x; 1.8309x over previous
//
#include <hip/hip_runtime.h>
#include <math.h>

#define NB     16384
#define NTOT   427
#define NROI   30
#define TDIM   10
#define HDIM   64
#define FCD    32
#define NHD    256
#define NROIF  300
#define NOTHER 127
#define ACTD   31
#define NSEQ   (NB*NROI)
#define COMB   1216

typedef __attribute__((ext_vector_type(8))) short bf16x8;
typedef __attribute__((ext_vector_type(4))) float f32x4;

__device__ __forceinline__ float sigmf(float v) { return 1.0f / (1.0f + __expf(-v)); }
__device__ __forceinline__ float tanh_fast(float v) {
    float e = __expf(2.0f * v);
    return 1.0f - 2.0f / (e + 1.0f);
}
__device__ __forceinline__ short f2bf(float f) {   // RNE
    unsigned u = __builtin_bit_cast(unsigned, f);
    u += 0x7fff + ((u >> 16) & 1);
    return (short)(u >> 16);
}
__device__ __forceinline__ float bf2f(short s) {
    return __builtin_bit_cast(float, ((unsigned)(unsigned short)s) << 16);
}

// swizzled element index for H tiles: element (m, u) of a 64x64 bf16 tile.
// chunk (16B = 8 bf16) index is XORed with (m&7) -> stride-128B reads spread
// across all 8 chunks of a row group (G4 fix).
__device__ __forceinline__ int hswz(int m, int u) {
    return m * 64 + ((((u >> 3) ^ (m & 7)) << 3) | (u & 7));
}

// ---------------------------------------------------------------------------
// MLP layer: out[M=16384][256] = relu(in[M][K] @ W^T + b)   (unchanged, fp32)
// ---------------------------------------------------------------------------
template<int KDIM>
__global__ __launch_bounds__(256) void mlp_kernel(
    const float* __restrict__ in, int ld_in,
    const float* __restrict__ W, const float* __restrict__ bias,
    float* __restrict__ out, int ld_out)
{
    __shared__ float in_t[32][68];
    __shared__ float w_t[32][260];

    const int tid = threadIdx.x;
    const int m0  = blockIdx.x * 64;
    const int a   = tid & 7;
    const int bc  = tid >> 3;

    float acc[8][8];
    #pragma unroll
    for (int i = 0; i < 8; i++)
        #pragma unroll
        for (int jj = 0; jj < 8; jj++) acc[i][jj] = 0.0f;

    for (int k0 = 0; k0 < KDIM; k0 += 32) {
        __syncthreads();
        #pragma unroll
        for (int e = 0; e < 8; e++) {
            int idx = tid + e * 256;
            int k = idx & 31, m = idx >> 5;
            float v = 0.0f;
            if ((KDIM % 32 == 0) || (k0 + k < KDIM))
                v = in[(size_t)(m0 + m) * ld_in + k0 + k];
            in_t[k][m] = v;
        }
        {
            const int j = tid;
            #pragma unroll
            for (int e = 0; e < 8; e++) {
                #pragma unroll
                for (int qq = 0; qq < 4; qq++) {
                    int k = e * 4 + qq;
                    float v = 0.0f;
                    if ((KDIM % 32 == 0) || (k0 + k < KDIM))
                        v = W[(size_t)j * KDIM + k0 + k];
                    w_t[k][j] = v;
                }
            }
        }
        __syncthreads();
        #pragma unroll 4
        for (int k = 0; k < 32; k++) {
            float av[8], wv[8];
            #pragma unroll
            for (int i = 0; i < 8; i++)  av[i] = in_t[k][a * 8 + i];
            #pragma unroll
            for (int jj = 0; jj < 8; jj++) wv[jj] = w_t[k][bc * 8 + jj];
            #pragma unroll
            for (int i = 0; i < 8; i++)
                #pragma unroll
                for (int jj = 0; jj < 8; jj++)
                    acc[i][jj] = __fmaf_rn(av[i], wv[jj], acc[i][jj]);
        }
    }

    float bv[8];
    #pragma unroll
    for (int jj = 0; jj < 8; jj++) bv[jj] = bias[bc * 8 + jj];
    #pragma unroll
    for (int i = 0; i < 8; i++) {
        float* orow = out + (size_t)(m0 + a * 8 + i) * ld_out + bc * 8;
        #pragma unroll
        for (int jj = 0; jj < 8; jj++) {
            float v = acc[i][jj] + bv[jj];
            orow[jj] = v > 0.0f ? v : 0.0f;
        }
    }
}

// ---------------------------------------------------------------------------
// Fused bidirectional LSTM + FC, MFMA version. 64 seqs / block, 256 threads.
//
// Per step GEMM: D[m=seq 64][n=gate 256] = h[64x64] @ Whh^T[64x256], K=64,
// via mfma_f32_16x16x32_bf16. Wave w owns N-tiles {q*4+w, q=0..3} so each
// lane holds all 4 gate types of unit u = w*16 + (lane&15) for 16 seqs
// (4 mtiles x 4 regs) -> cell update entirely lane-local, c in registers.
// h round-trips through an XOR-swizzled 64x64 bf16 LDS tile.
// K-fragment order is assumed contiguous-8 per lane for BOTH A and B; any
// consistent k-permutation cancels in the MFMA dot product.
// ---------------------------------------------------------------------------
__global__ __launch_bounds__(256) void lstm_fc_mfma(
    const float* __restrict__ x,
    const float* __restrict__ Wih_f, const float* __restrict__ Whh_f,
    const float* __restrict__ bih_f, const float* __restrict__ bhh_f,
    const float* __restrict__ Wih_b, const float* __restrict__ Whh_b,
    const float* __restrict__ bih_b, const float* __restrict__ bhh_b,
    const float* __restrict__ Wfc, const float* __restrict__ bfc,
    float* __restrict__ combined)
{
    __shared__ short Hf[64 * 64];      // 8 KB, swizzled [seq][unit]
    __shared__ short Hb[64 * 64];      // 8 KB
    __shared__ float Xs[64][TDIM];     // 2.5 KB
    __shared__ int   lens_s[64];
    __shared__ float wfc_s[FCD][128];  // 16 KB
    __shared__ float bfc_s[FCD];

    const int tid    = threadIdx.x;
    const int w      = tid >> 6;       // wave 0..3
    const int lane   = tid & 63;
    const int n0     = lane & 15;
    const int kq     = lane >> 4;      // 0..3
    const int s0base = blockIdx.x * 64;

    // stage X + FC weights
    for (int idx = tid; idx < 64 * TDIM; idx += 256) {
        int s = idx / TDIM, t = idx - s * TDIM;
        int gs = s0base + s;
        int row = gs / NROI, r = gs - row * NROI;
        Xs[s][t] = x[(size_t)row * NTOT + r * TDIM + t];
    }
    for (int idx = tid; idx < FCD * 128; idx += 256)
        wfc_s[idx >> 7][idx & 127] = Wfc[idx];
    if (tid < FCD) bfc_s[tid] = bfc[tid];
    __syncthreads();
    if (tid < 64) {
        int c = 0;
        #pragma unroll
        for (int t = 0; t < TDIM; t++) c += (Xs[tid][t] != 0.0f) ? 1 : 0;
        lens_s[tid] = c;
    }
    // lens_s visible after the barrier inside the dir loop (post H-zero).

    const int ubase = w * 16 + n0;     // this lane's unit

    for (int dir = 0; dir < 2; dir++) {
        const float* Whh  = dir ? Whh_b : Whh_f;
        const float* Wih  = dir ? Wih_b : Wih_f;
        const float* bihp = dir ? bih_b : bih_f;
        const float* bhhp = dir ? bhh_b : bhh_f;
        short* H = dir ? Hb : Hf;

        // B fragments: WhhT[k][n], n = (q*4+w)*16 + n0, k = half*32 + kq*8 + j
        bf16x8 bfrag[4][2];
        float  wih_r[4], bb_r[4];
        #pragma unroll
        for (int q = 0; q < 4; q++) {
            const int n = (q * 4 + w) * 16 + n0;
            wih_r[q] = Wih[n];
            bb_r[q]  = bihp[n] + bhhp[n];
            #pragma unroll
            for (int half = 0; half < 2; half++) {
                const float* src = Whh + (size_t)n * HDIM + half * 32 + kq * 8;
                bf16x8 f;
                #pragma unroll
                for (int j = 0; j < 8; j++) f[j] = f2bf(src[j]);
                bfrag[q][half] = f;
            }
        }

        float cst[4][4];
        #pragma unroll
        for (int mt = 0; mt < 4; mt++)
            #pragma unroll
            for (int r = 0; r < 4; r++) cst[mt][r] = 0.0f;

        for (int idx = tid; idx < 64 * 64; idx += 256) H[idx] = 0;
        __syncthreads();

        for (int step = 0; step < TDIM; step++) {
            const int t = dir ? (TDIM - 1 - step) : step;

            // A fragments: h[m][k], m = mt*16 + n0, k = half*32 + kq*8 ..+7
            bf16x8 afrag[4][2];
            #pragma unroll
            for (int mt = 0; mt < 4; mt++) {
                const int m  = mt * 16 + n0;
                const int sm = m & 7;
                #pragma unroll
                for (int half = 0; half < 2; half++) {
                    const int c16 = half * 4 + kq;
                    afrag[mt][half] =
                        *(const bf16x8*)&H[m * 64 + (((c16 ^ sm)) << 3)];
                }
            }

            f32x4 acc[4][4];
            const f32x4 z = {0.0f, 0.0f, 0.0f, 0.0f};
            #pragma unroll
            for (int mt = 0; mt < 4; mt++)
                #pragma unroll
                for (int q = 0; q < 4; q++) {
                    f32x4 p = __builtin_amdgcn_mfma_f32_16x16x32_bf16(
                        afrag[mt][0], bfrag[q][0], z, 0, 0, 0);
                    acc[mt][q] = __builtin_amdgcn_mfma_f32_16x16x32_bf16(
                        afrag[mt][1], bfrag[q][1], p, 0, 0, 0);
                }

            __syncthreads();   // all waves' A-reads done before H writes

            #pragma unroll
            for (int mt = 0; mt < 4; mt++) {
                #pragma unroll
                for (int r = 0; r < 4; r++) {
                    const int m  = mt * 16 + kq * 4 + r;
                    const float xv = Xs[m][t];
                    const bool msk = (t < lens_s[m]);
                    float gi = acc[mt][0][r] + xv * wih_r[0] + bb_r[0];
                    float gf = acc[mt][1][r] + xv * wih_r[1] + bb_r[1];
                    float gg = acc[mt][2][r] + xv * wih_r[2] + bb_r[2];
                    float go = acc[mt][3][r] + xv * wih_r[3] + bb_r[3];
                    float cn = sigmf(gf) * cst[mt][r] + sigmf(gi) * tanh_fast(gg);
                    float hn = sigmf(go) * tanh_fast(cn);
                    if (msk) {
                        cst[mt][r] = cn;
                        H[hswz(m, ubase)] = f2bf(hn);
                    }
                }
            }
            __syncthreads();   // H writes done before next step's reads
        }
    }

    // FC epilogue: roi_out[s][f] = relu(bfc[f] + hf.Wfc[f][:64] + hb.Wfc[f][64:])
    {
        const int s  = tid & 63;
        const int fg = tid >> 6;
        const int sx = s * 64, sm = s & 7;
        float facc[8];
        #pragma unroll
        for (int ff = 0; ff < 8; ff++) facc[ff] = bfc_s[fg * 8 + ff];
        #pragma unroll
        for (int c = 0; c < 8; c++) {
            bf16x8 vf = *(const bf16x8*)&Hf[sx + ((c ^ sm) << 3)];
            bf16x8 vb = *(const bf16x8*)&Hb[sx + ((c ^ sm) << 3)];
            #pragma unroll
            for (int j = 0; j < 8; j++) {
                const float hfv = bf2f(vf[j]);
                const float hbv = bf2f(vb[j]);
                const int u = c * 8 + j;
                #pragma unroll
                for (int ff = 0; ff < 8; ff++)
                    facc[ff] += hfv * wfc_s[fg * 8 + ff][u]
                              + hbv * wfc_s[fg * 8 + ff][64 + u];
            }
        }
        const int gs  = s0base + s;
        const int row = gs / NROI, r = gs - row * NROI;
        float* orow = combined + (size_t)row * COMB + r * FCD + fg * 8;
        #pragma unroll
        for (int ff = 0; ff < 8; ff++) {
            float v = facc[ff];
            orow[ff] = v > 0.0f ? v : 0.0f;
        }
    }
}

// ---------------------------------------------------------------------------
// Output projection: q[row][j] = b_out[j] + combined[row] . W_out[j]
// ---------------------------------------------------------------------------
__global__ void qout_kernel(const float* __restrict__ combined,
                            const float* __restrict__ Wout,
                            const float* __restrict__ bout,
                            float* __restrict__ q)
{
    const int j   = threadIdx.x;              // 0..30
    const int r   = threadIdx.y;              // 0..7
    const int row = blockIdx.x * 8 + r;
    const float4* crow = (const float4*)(combined + (size_t)row * COMB);
    const float4* wrow = (const float4*)(Wout + (size_t)j * COMB);
    float acc = bout[j];
    #pragma unroll 4
    for (int k4 = 0; k4 < COMB / 4; k4++) {
        float4 c4 = crow[k4];
        float4 w4 = wrow[k4];
        acc += c4.x * w4.x + c4.y * w4.y + c4.z * w4.z + c4.w * w4.w;
    }
    q[(size_t)row * ACTD + j] = acc;
}

// ---------------------------------------------------------------------------
extern "C" void kernel_launch(void* const* d_in, const int* in_sizes, int n_in,
                              void* d_out, int out_size, void* d_ws, size_t ws_size,
                              hipStream_t stream)
{
    (void)in_sizes; (void)n_in; (void)out_size;
    const float* x     = (const float*)d_in[0];
    const float* Wih_f = (const float*)d_in[1];
    const float* Whh_f = (const float*)d_in[2];
    const float* bih_f = (const float*)d_in[3];
    const float* bhh_f = (const float*)d_in[4];
    const float* Wih_b = (const float*)d_in[5];
    const float* Whh_b = (const float*)d_in[6];
    const float* bih_b = (const float*)d_in[7];
    const float* bhh_b = (const float*)d_in[8];
    const float* Wfc   = (const float*)d_in[9];
    const float* bfc   = (const float*)d_in[10];
    const float* W1    = (const float*)d_in[11];
    const float* b1    = (const float*)d_in[12];
    const float* W2    = (const float*)d_in[13];
    const float* b2    = (const float*)d_in[14];
    const float* W3    = (const float*)d_in[15];
    const float* b3    = (const float*)d_in[16];
    const float* Wout  = (const float*)d_in[17];
    const float* bout  = (const float*)d_in[18];
    float* q        = (float*)d_out;
    float* combined = (float*)d_ws;   // 16384 x 1216 f32 = 79.7 MB

    if (ws_size < (size_t)NB * COMB * sizeof(float)) return;

    mlp_kernel<NOTHER><<<NB / 64, 256, 0, stream>>>(x + NROIF, NTOT, W1, b1, combined, COMB);
    mlp_kernel<NHD><<<NB / 64, 256, 0, stream>>>(combined, COMB, W2, b2, combined + 256, COMB);
    mlp_kernel<NHD><<<NB / 64, 256, 0, stream>>>(combined + 256, COMB, W3, b3, combined + 960, COMB);

    lstm_fc_mfma<<<NSEQ / 64, 256, 0, stream>>>(x, Wih_f, Whh_f, bih_f, bhh_f,
                                                Wih_b, Whh_b, bih_b, bhh_b,
                                                Wfc, bfc, combined);

    qout_kernel<<<NB / 8, dim3(31, 8), 0, stream>>>(combined, Wout, bout, q);
}

// Round 3
// 1293.985 us; speedup vs baseline: 4.9886x; 2.7246x over previous
//
#include <hip/hip_runtime.h>
#include <math.h>

#define NB     16384
#define NTOT   427
#define NROI   30
#define TDIM   10
#define HDIM   64
#define FCD    32
#define NHD    256
#define NROIF  300
#define NOTHER 127
#define ACTD   31
#define NSEQ   (NB*NROI)
#define COMB   1216
#define LOG2E  1.44269504f

typedef __attribute__((ext_vector_type(8))) short bf16x8;
typedef __attribute__((ext_vector_type(4))) float f32x4;

// raw-rate transcendentals (1 inst each; ~1 ulp — fine vs 1.05e-2 threshold)
__device__ __forceinline__ float fexp2(float x){ float r; asm("v_exp_f32 %0, %1":"=v"(r):"v"(x)); return r; }
__device__ __forceinline__ float frcp (float x){ float r; asm("v_rcp_f32 %0, %1":"=v"(r):"v"(x)); return r; }
// sigmoid: 1/(1+2^(-x*log2e)); tanh: 1 - 2/(1+2^(2x*log2e)). Saturation safe.
__device__ __forceinline__ float sigmf(float v){ return frcp(1.0f + fexp2(-LOG2E * v)); }
__device__ __forceinline__ float tanhf_(float v){ return __fmaf_rn(-2.0f, frcp(1.0f + fexp2((2.0f*LOG2E) * v)), 1.0f); }

__device__ __forceinline__ short f2bf(float f) {   // RNE f32->bf16
    unsigned u = __builtin_bit_cast(unsigned, f);
    u += 0x7fff + ((u >> 16) & 1);
    return (short)(u >> 16);
}
__device__ __forceinline__ float bf2f(short s) {
    return __builtin_bit_cast(float, ((unsigned)(unsigned short)s) << 16);
}

// ---------------------------------------------------------------------------
// MLP layer: out[M=16384][256] = relu(in[M][K] @ W^T + b)   (fp32, unchanged)
// ---------------------------------------------------------------------------
template<int KDIM>
__global__ __launch_bounds__(256) void mlp_kernel(
    const float* __restrict__ in, int ld_in,
    const float* __restrict__ W, const float* __restrict__ bias,
    float* __restrict__ out, int ld_out)
{
    __shared__ float in_t[32][68];
    __shared__ float w_t[32][260];

    const int tid = threadIdx.x;
    const int m0  = blockIdx.x * 64;
    const int a   = tid & 7;
    const int bc  = tid >> 3;

    float acc[8][8];
    #pragma unroll
    for (int i = 0; i < 8; i++)
        #pragma unroll
        for (int jj = 0; jj < 8; jj++) acc[i][jj] = 0.0f;

    for (int k0 = 0; k0 < KDIM; k0 += 32) {
        __syncthreads();
        #pragma unroll
        for (int e = 0; e < 8; e++) {
            int idx = tid + e * 256;
            int k = idx & 31, m = idx >> 5;
            float v = 0.0f;
            if ((KDIM % 32 == 0) || (k0 + k < KDIM))
                v = in[(size_t)(m0 + m) * ld_in + k0 + k];
            in_t[k][m] = v;
        }
        {
            const int j = tid;
            #pragma unroll
            for (int e = 0; e < 8; e++) {
                #pragma unroll
                for (int qq = 0; qq < 4; qq++) {
                    int k = e * 4 + qq;
                    float v = 0.0f;
                    if ((KDIM % 32 == 0) || (k0 + k < KDIM))
                        v = W[(size_t)j * KDIM + k0 + k];
                    w_t[k][j] = v;
                }
            }
        }
        __syncthreads();
        #pragma unroll 4
        for (int k = 0; k < 32; k++) {
            float av[8], wv[8];
            #pragma unroll
            for (int i = 0; i < 8; i++)  av[i] = in_t[k][a * 8 + i];
            #pragma unroll
            for (int jj = 0; jj < 8; jj++) wv[jj] = w_t[k][bc * 8 + jj];
            #pragma unroll
            for (int i = 0; i < 8; i++)
                #pragma unroll
                for (int jj = 0; jj < 8; jj++)
                    acc[i][jj] = __fmaf_rn(av[i], wv[jj], acc[i][jj]);
        }
    }

    float bv[8];
    #pragma unroll
    for (int jj = 0; jj < 8; jj++) bv[jj] = bias[bc * 8 + jj];
    #pragma unroll
    for (int i = 0; i < 8; i++) {
        float* orow = out + (size_t)(m0 + a * 8 + i) * ld_out + bc * 8;
        #pragma unroll
        for (int jj = 0; jj < 8; jj++) {
            float v = acc[i][jj] + bv[jj];
            orow[jj] = v > 0.0f ? v : 0.0f;
        }
    }
}

// ---------------------------------------------------------------------------
// Fused bidirectional LSTM + FC, MFMA + ping-pong H (1 barrier/step).
// 64 seqs / block, 256 threads / 4 waves.
// Hbuf[0]: dir0 even-step buffer (holds final hf); Hbuf[2]: dir1 even-step
// buffer (holds final hb); Hbuf[1]: shared odd-step buffer.
// Lane (w, n0=lane&15, kq=lane>>4) owns cells (m = mt*16+kq*4+r, u = w*16+n0);
// c in regs, old-h re-read from the read buffer (pre-barrier safe).
// FC epilogue = one 64x32x128 MFMA GEMM off the bf16 H tiles.
// ---------------------------------------------------------------------------
__global__ __launch_bounds__(256, 4) void lstm_fc_mfma(
    const float* __restrict__ x,
    const float* __restrict__ Wih_f, const float* __restrict__ Whh_f,
    const float* __restrict__ bih_f, const float* __restrict__ bhh_f,
    const float* __restrict__ Wih_b, const float* __restrict__ Whh_b,
    const float* __restrict__ bih_b, const float* __restrict__ bhh_b,
    const float* __restrict__ Wfc, const float* __restrict__ bfc,
    float* __restrict__ combined)
{
    __shared__ short Hbuf[3][64 * 64];   // 24 KB
    __shared__ float Xs[TDIM][64];       // 2.5 KB, [t][seq]
    __shared__ int   lens_s[64];

    const int tid    = threadIdx.x;
    const int w      = tid >> 6;
    const int lane   = tid & 63;
    const int n0     = lane & 15;
    const int kq     = lane >> 4;
    const int s0base = blockIdx.x * 64;

    for (int idx = tid; idx < 64 * TDIM; idx += 256) {
        int s = idx & 63, t = idx >> 6;
        int gs = s0base + s;
        int row = gs / NROI, r = gs - row * NROI;
        Xs[t][s] = x[(size_t)row * NTOT + r * TDIM + t];
    }
    __syncthreads();
    if (tid < 64) {
        int c = 0;
        #pragma unroll
        for (int t = 0; t < TDIM; t++) c += (Xs[t][tid] != 0.0f) ? 1 : 0;
        lens_s[tid] = c;
    }
    for (int idx = tid; idx < 64 * 64; idx += 256) {
        Hbuf[0][idx] = 0; Hbuf[2][idx] = 0;
    }
    __syncthreads();

    // packed lens (2 per reg) for this lane's 16 cells: cell c -> m=(c>>2)*16+kq*4+(c&3)
    int lenpk[8];
    #pragma unroll
    for (int i = 0; i < 8; i++) {
        const int c0 = 2 * i, c1 = 2 * i + 1;
        const int mA = (c0 >> 2) * 16 + kq * 4 + (c0 & 3);
        const int mB = (c1 >> 2) * 16 + kq * 4 + (c1 & 3);
        lenpk[i] = lens_s[mA] | (lens_s[mB] << 16);
    }

    const int ubase = w * 16 + n0;
    const int uhi = ubase >> 3, ulo = ubase & 7;

    for (int dir = 0; dir < 2; dir++) {
        const float* Whh  = dir ? Whh_b : Whh_f;
        const float* Wih  = dir ? Wih_b : Wih_f;
        const float* bihp = dir ? bih_b : bih_f;
        const float* bhhp = dir ? bhh_b : bhh_f;
        short* bufE = Hbuf[dir ? 2 : 0];
        short* bufO = Hbuf[1];

        // B fragments: WhhT[k][n], n = (q*4+w)*16 + n0, k = half*32 + kq*8 + j
        bf16x8 bfrag[4][2];
        float  wih_r[4], bb_r[4];
        #pragma unroll
        for (int q = 0; q < 4; q++) {
            const int n = (q * 4 + w) * 16 + n0;
            wih_r[q] = Wih[n];
            bb_r[q]  = bihp[n] + bhhp[n];
            #pragma unroll
            for (int half = 0; half < 2; half++) {
                const float* src = Whh + (size_t)n * HDIM + half * 32 + kq * 8;
                bf16x8 f;
                #pragma unroll
                for (int j = 0; j < 8; j++) f[j] = f2bf(src[j]);
                bfrag[q][half] = f;
            }
        }

        float c16[16];
        #pragma unroll
        for (int i = 0; i < 16; i++) c16[i] = 0.0f;

        for (int step = 0; step < TDIM; step++) {
            const int t = dir ? (TDIM - 1 - step) : step;
            short* rb = (step & 1) ? bufO : bufE;
            short* wb = (step & 1) ? bufE : bufO;

            #pragma unroll
            for (int mt = 0; mt < 4; mt++) {
                // A fragment rows m = mt*16 + n0
                const int ma = mt * 16 + n0;
                const int sa = ma & 7;
                bf16x8 a0 = *(const bf16x8*)&rb[ma * 64 + ((kq ^ sa) << 3)];
                bf16x8 a1 = *(const bf16x8*)&rb[ma * 64 + (((4 + kq) ^ sa) << 3)];

                f32x4 acc[4];
                const f32x4 z = {0.0f, 0.0f, 0.0f, 0.0f};
                #pragma unroll
                for (int q = 0; q < 4; q++) {
                    f32x4 p = __builtin_amdgcn_mfma_f32_16x16x32_bf16(a0, bfrag[q][0], z, 0, 0, 0);
                    acc[q] = __builtin_amdgcn_mfma_f32_16x16x32_bf16(a1, bfrag[q][1], p, 0, 0, 0);
                }

                #pragma unroll
                for (int r = 0; r < 4; r++) {
                    const int cidx = mt * 4 + r;
                    const int mm   = mt * 16 + kq * 4 + r;
                    const float xv = Xs[t][mm];
                    const int len  = (lenpk[cidx >> 1] >> ((cidx & 1) * 16)) & 0xffff;
                    const bool msk = t < len;
                    float gi = acc[0][r] + __fmaf_rn(xv, wih_r[0], bb_r[0]);
                    float gf = acc[1][r] + __fmaf_rn(xv, wih_r[1], bb_r[1]);
                    float gg = acc[2][r] + __fmaf_rn(xv, wih_r[2], bb_r[2]);
                    float go = acc[3][r] + __fmaf_rn(xv, wih_r[3], bb_r[3]);
                    const int hidx = (mm << 6) + (((uhi ^ mm) & 7) << 3) + ulo;
                    float hold = bf2f(rb[hidx]);
                    float cp = c16[cidx];
                    float cn = __fmaf_rn(sigmf(gf), cp, sigmf(gi) * tanhf_(gg));
                    float hn = sigmf(go) * tanhf_(cn);
                    c16[cidx] = msk ? cn : cp;
                    wb[hidx]  = f2bf(msk ? hn : hold);
                }
            }
            __syncthreads();   // wb complete before it becomes next step's rb
        }
        // final h of this dir is in bufE (step 9 writes bufE)
    }

    __builtin_amdgcn_sched_barrier(0);   // keep epilogue loads out of LSTM loop

    // ---- FC epilogue as MFMA: D[64s x 32f] = [Hf|Hb][64x128] @ Wfc^T ----
    {
        const short* Hf = Hbuf[0];
        const short* Hb = Hbuf[2];

        bf16x8 wfr[2][4];
        float  bias[2];
        #pragma unroll
        for (int nt = 0; nt < 2; nt++) {
            const int f = nt * 16 + n0;
            bias[nt] = bfc[f];
            #pragma unroll
            for (int kc = 0; kc < 4; kc++) {
                const float* src = Wfc + (size_t)f * 128 + kc * 32 + kq * 8;
                bf16x8 v;
                #pragma unroll
                for (int j = 0; j < 8; j++) v[j] = f2bf(src[j]);
                wfr[nt][kc] = v;
            }
        }

        const int ma = w * 16 + n0;
        const int sa = ma & 7;
        bf16x8 afr[4];
        #pragma unroll
        for (int kc = 0; kc < 2; kc++) {
            afr[kc]     = *(const bf16x8*)&Hf[ma * 64 + (((kc * 4 + kq) ^ sa) << 3)];
            afr[kc + 2] = *(const bf16x8*)&Hb[ma * 64 + (((kc * 4 + kq) ^ sa) << 3)];
        }

        f32x4 acc[2];
        #pragma unroll
        for (int nt = 0; nt < 2; nt++) {
            f32x4 z = {0.0f, 0.0f, 0.0f, 0.0f};
            acc[nt] = z;
            #pragma unroll
            for (int kc = 0; kc < 4; kc++)
                acc[nt] = __builtin_amdgcn_mfma_f32_16x16x32_bf16(afr[kc], wfr[nt][kc], acc[nt], 0, 0, 0);
        }

        #pragma unroll
        for (int nt = 0; nt < 2; nt++) {
            #pragma unroll
            for (int r = 0; r < 4; r++) {
                const int s   = w * 16 + kq * 4 + r;
                const int gs  = s0base + s;
                const int row = gs / NROI, rr = gs - row * NROI;
                float v = acc[nt][r] + bias[nt];
                combined[(size_t)row * COMB + rr * FCD + nt * 16 + n0] = v > 0.0f ? v : 0.0f;
            }
        }
    }
}

// ---------------------------------------------------------------------------
// Output projection: q[row][j] = b_out[j] + combined[row] . W_out[j]
// ---------------------------------------------------------------------------
__global__ __launch_bounds__(256) void qout_kernel(
    const float* __restrict__ combined,
    const float* __restrict__ Wout,
    const float* __restrict__ bout,
    float* __restrict__ q)
{
    const int j   = threadIdx.x;              // 0..31 (31 masked)
    const int r   = threadIdx.y;              // 0..7
    const int row = blockIdx.x * 8 + r;
    if (j >= ACTD) return;
    const float4* crow = (const float4*)(combined + (size_t)row * COMB);
    const float4* wrow = (const float4*)(Wout + (size_t)j * COMB);
    float acc = bout[j];
    #pragma unroll 4
    for (int k4 = 0; k4 < COMB / 4; k4++) {
        float4 c4 = crow[k4];
        float4 w4 = wrow[k4];
        acc += c4.x * w4.x + c4.y * w4.y + c4.z * w4.z + c4.w * w4.w;
    }
    q[(size_t)row * ACTD + j] = acc;
}

// ---------------------------------------------------------------------------
extern "C" void kernel_launch(void* const* d_in, const int* in_sizes, int n_in,
                              void* d_out, int out_size, void* d_ws, size_t ws_size,
                              hipStream_t stream)
{
    (void)in_sizes; (void)n_in; (void)out_size;
    const float* x     = (const float*)d_in[0];
    const float* Wih_f = (const float*)d_in[1];
    const float* Whh_f = (const float*)d_in[2];
    const float* bih_f = (const float*)d_in[3];
    const float* bhh_f = (const float*)d_in[4];
    const float* Wih_b = (const float*)d_in[5];
    const float* Whh_b = (const float*)d_in[6];
    const float* bih_b = (const float*)d_in[7];
    const float* bhh_b = (const float*)d_in[8];
    const float* Wfc   = (const float*)d_in[9];
    const float* bfc   = (const float*)d_in[10];
    const float* W1    = (const float*)d_in[11];
    const float* b1    = (const float*)d_in[12];
    const float* W2    = (const float*)d_in[13];
    const float* b2    = (const float*)d_in[14];
    const float* W3    = (const float*)d_in[15];
    const float* b3    = (const float*)d_in[16];
    const float* Wout  = (const float*)d_in[17];
    const float* bout  = (const float*)d_in[18];
    float* q        = (float*)d_out;
    float* combined = (float*)d_ws;   // 16384 x 1216 f32 = 79.7 MB

    if (ws_size < (size_t)NB * COMB * sizeof(float)) return;

    mlp_kernel<NOTHER><<<NB / 64, 256, 0, stream>>>(x + NROIF, NTOT, W1, b1, combined, COMB);
    mlp_kernel<NHD><<<NB / 64, 256, 0, stream>>>(combined, COMB, W2, b2, combined + 256, COMB);
    mlp_kernel<NHD><<<NB / 64, 256, 0, stream>>>(combined + 256, COMB, W3, b3, combined + 960, COMB);

    lstm_fc_mfma<<<NSEQ / 64, 256, 0, stream>>>(x, Wih_f, Whh_f, bih_f, bhh_f,
                                                Wih_b, Whh_b, bih_b, bhh_b,
                                                Wfc, bfc, combined);

    qout_kernel<<<NB / 8, dim3(32, 8), 0, stream>>>(combined, Wout, bout, q);
}

// Round 6
// 1256.379 us; speedup vs baseline: 5.1379x; 1.0299x over previous
//
#include <hip/hip_runtime.h>
#include <math.h>

#define NB     16384
#define NTOT   427
#define NROI   30
#define TDIM   10
#define HDIM   64
#define FCD    32
#define NHD    256
#define NROIF  300
#define NOTHER 127
#define ACTD   31
#define NSEQ   (NB*NROI)
#define COMB   1216
#define LOG2E  1.44269504f

typedef __attribute__((ext_vector_type(8))) short bf16x8;
typedef __attribute__((ext_vector_type(4))) float f32x4;
typedef __attribute__((ext_vector_type(2))) float f32x2;

// scalar raw-rate transcendentals (proven numerically fine in R3)
__device__ __forceinline__ float fexp2(float x){ float r; asm("v_exp_f32 %0, %1":"=v"(r):"v"(x)); return r; }
__device__ __forceinline__ float frcp (float x){ float r; asm("v_rcp_f32 %0, %1":"=v"(r):"v"(x)); return r; }
__device__ __forceinline__ f32x2 exp2v(f32x2 v){ f32x2 r; r.x = fexp2(v.x); r.y = fexp2(v.y); return r; }

// NOTE (R5 bisect): hand-written "v_pk_fma_f32/v_pk_mul_f32/v_pk_add_f32"
// inline asm is REMOVED — all packed math is native f32x2 C arithmetic so the
// compiler owns the VOP3P encodings (op_sel/op_sel_hi). R4/R5 failed at
// ~4-5e-2 absmax with hand-written pk asm; fold/batched-rcp error bounds are
// ~4e-7 relative, so the asm encodings are the prime suspect.

// RNE f32->bf16 (explicit; do NOT use v_cvt_pk_bf16_f32 in the recurrence)
__device__ __forceinline__ short f2bf(float f) {
    unsigned u = __builtin_bit_cast(unsigned, f);
    u += 0x7fff + ((u >> 16) & 1);
    return (short)(u >> 16);
}
__device__ __forceinline__ float bf2f(short s) {
    return __builtin_bit_cast(float, ((unsigned)(unsigned short)s) << 16);
}

// ---------------------------------------------------------------------------
// MLP layer: out[M=16384][256] = relu(in[M][K] @ W^T + b)   (fp32, unchanged)
// ---------------------------------------------------------------------------
template<int KDIM>
__global__ __launch_bounds__(256) void mlp_kernel(
    const float* __restrict__ in, int ld_in,
    const float* __restrict__ W, const float* __restrict__ bias,
    float* __restrict__ out, int ld_out)
{
    __shared__ float in_t[32][68];
    __shared__ float w_t[32][260];

    const int tid = threadIdx.x;
    const int m0  = blockIdx.x * 64;
    const int a   = tid & 7;
    const int bc  = tid >> 3;

    float acc[8][8];
    #pragma unroll
    for (int i = 0; i < 8; i++)
        #pragma unroll
        for (int jj = 0; jj < 8; jj++) acc[i][jj] = 0.0f;

    for (int k0 = 0; k0 < KDIM; k0 += 32) {
        __syncthreads();
        #pragma unroll
        for (int e = 0; e < 8; e++) {
            int idx = tid + e * 256;
            int k = idx & 31, m = idx >> 5;
            float v = 0.0f;
            if ((KDIM % 32 == 0) || (k0 + k < KDIM))
                v = in[(size_t)(m0 + m) * ld_in + k0 + k];
            in_t[k][m] = v;
        }
        {
            const int j = tid;
            #pragma unroll
            for (int e = 0; e < 8; e++) {
                #pragma unroll
                for (int qq = 0; qq < 4; qq++) {
                    int k = e * 4 + qq;
                    float v = 0.0f;
                    if ((KDIM % 32 == 0) || (k0 + k < KDIM))
                        v = W[(size_t)j * KDIM + k0 + k];
                    w_t[k][j] = v;
                }
            }
        }
        __syncthreads();
        #pragma unroll 4
        for (int k = 0; k < 32; k++) {
            float av[8], wv[8];
            #pragma unroll
            for (int i = 0; i < 8; i++)  av[i] = in_t[k][a * 8 + i];
            #pragma unroll
            for (int jj = 0; jj < 8; jj++) wv[jj] = w_t[k][bc * 8 + jj];
            #pragma unroll
            for (int i = 0; i < 8; i++)
                #pragma unroll
                for (int jj = 0; jj < 8; jj++)
                    acc[i][jj] = __fmaf_rn(av[i], wv[jj], acc[i][jj]);
        }
    }

    float bv[8];
    #pragma unroll
    for (int jj = 0; jj < 8; jj++) bv[jj] = bias[bc * 8 + jj];
    #pragma unroll
    for (int i = 0; i < 8; i++) {
        float* orow = out + (size_t)(m0 + a * 8 + i) * ld_out + bc * 8;
        #pragma unroll
        for (int jj = 0; jj < 8; jj++) {
            float v = acc[i][jj] + bv[jj];
            orow[jj] = v > 0.0f ? v : 0.0f;
        }
    }
}

// ---------------------------------------------------------------------------
// Fused bidirectional LSTM + FC, MFMA + f32x2 cell math (compiler-encoded).
// Gate-scaled weights (s_q = -log2e for i,f,o; +2log2e for g) so MFMA output
// feeds v_exp_f32 directly; bias rides in the MFMA C operand. Batched
// reciprocals: 1 rcp per 4 gate denominators, 1 per 2 tanh(c) denominators.
// ---------------------------------------------------------------------------
__global__ __launch_bounds__(256, 4) void lstm_fc_mfma(
    const float* __restrict__ x,
    const float* __restrict__ Wih_f, const float* __restrict__ Whh_f,
    const float* __restrict__ bih_f, const float* __restrict__ bhh_f,
    const float* __restrict__ Wih_b, const float* __restrict__ Whh_b,
    const float* __restrict__ bih_b, const float* __restrict__ bhh_b,
    const float* __restrict__ Wfc, const float* __restrict__ bfc,
    float* __restrict__ combined)
{
    __shared__ short Hbuf[3][64 * 64];   // 24 KB
    __shared__ float Xs[TDIM][64];       // 2.5 KB
    __shared__ int   lens_s[64];

    const int tid    = threadIdx.x;
    const int w      = tid >> 6;
    const int lane   = tid & 63;
    const int n0     = lane & 15;
    const int kq     = lane >> 4;
    const int s0base = blockIdx.x * 64;

    for (int idx = tid; idx < 64 * TDIM; idx += 256) {
        int s = idx & 63, t = idx >> 6;
        int gs = s0base + s;
        int row = gs / NROI, r = gs - row * NROI;
        Xs[t][s] = x[(size_t)row * NTOT + r * TDIM + t];
    }
    __syncthreads();
    if (tid < 64) {
        int c = 0;
        #pragma unroll
        for (int t = 0; t < TDIM; t++) c += (Xs[t][tid] != 0.0f) ? 1 : 0;
        lens_s[tid] = c;
    }
    for (int idx = tid; idx < 64 * 64; idx += 256) {
        Hbuf[0][idx] = 0; Hbuf[2][idx] = 0;
    }
    __syncthreads();

    // packed lens: lenpk[mt*2+pr] = len(cell r0) | len(cell r0+1)<<16
    int lenpk[8];
    #pragma unroll
    for (int i = 0; i < 8; i++) {
        const int c0 = 2 * i, c1 = 2 * i + 1;
        const int mA = (c0 >> 2) * 16 + kq * 4 + (c0 & 3);
        const int mB = (c1 >> 2) * 16 + kq * 4 + (c1 & 3);
        lenpk[i] = lens_s[mA] | (lens_s[mB] << 16);
    }

    const int ubase = w * 16 + n0;
    const int uhi = ubase >> 3, ulo = ubase & 7;

    for (int dir = 0; dir < 2; dir++) {
        const float* Whh  = dir ? Whh_b : Whh_f;
        const float* Wih  = dir ? Wih_b : Wih_f;
        const float* bihp = dir ? bih_b : bih_f;
        const float* bhhp = dir ? bhh_b : bhh_f;
        short* bufE = Hbuf[dir ? 2 : 0];
        short* bufO = Hbuf[1];

        // gate scales: q = gate type (i,f,g,o PyTorch order)
        const float sc0 = -LOG2E, sc2 = 2.0f * LOG2E;

        bf16x8 bfrag[4][2];
        float  wihS[4];
        f32x4  cinq[4];
        #pragma unroll
        for (int q = 0; q < 4; q++) {
            const float s_q = (q == 2) ? sc2 : sc0;
            const int n = (q * 4 + w) * 16 + n0;
            wihS[q] = s_q * Wih[n];
            const float bb = s_q * (bihp[n] + bhhp[n]);
            cinq[q][0] = bb; cinq[q][1] = bb; cinq[q][2] = bb; cinq[q][3] = bb;
            #pragma unroll
            for (int half = 0; half < 2; half++) {
                const float* src = Whh + (size_t)n * HDIM + half * 32 + kq * 8;
                bf16x8 f;
                #pragma unroll
                for (int j = 0; j < 8; j++) f[j] = f2bf(s_q * src[j]);
                bfrag[q][half] = f;
            }
        }

        f32x2 c2[8];
        #pragma unroll
        for (int i = 0; i < 8; i++) { c2[i].x = 0.0f; c2[i].y = 0.0f; }

        for (int step = 0; step < TDIM; step++) {
            const int t = dir ? (TDIM - 1 - step) : step;
            short* rb = (step & 1) ? bufO : bufE;
            short* wb = (step & 1) ? bufE : bufO;

            #pragma unroll
            for (int mt = 0; mt < 4; mt++) {
                const int ma = mt * 16 + n0;
                const int sa = ma & 7;
                bf16x8 a0 = *(const bf16x8*)&rb[ma * 64 + ((kq ^ sa) << 3)];
                bf16x8 a1 = *(const bf16x8*)&rb[ma * 64 + (((4 + kq) ^ sa) << 3)];

                f32x4 acc[4];
                #pragma unroll
                for (int q = 0; q < 4; q++) {
                    f32x4 p = __builtin_amdgcn_mfma_f32_16x16x32_bf16(a0, bfrag[q][0], cinq[q], 0, 0, 0);
                    acc[q] = __builtin_amdgcn_mfma_f32_16x16x32_bf16(a1, bfrag[q][1], p, 0, 0, 0);
                }

                #pragma unroll
                for (int pr = 0; pr < 2; pr++) {
                    const int r0  = 2 * pr;
                    const int mm  = mt * 16 + kq * 4 + r0;
                    const int lp  = lenpk[mt * 2 + pr];
                    const bool m0 = t < (lp & 0xffff);
                    const bool m1 = t < (lp >> 16);

                    f32x2 xv2 = *(const f32x2*)&Xs[t][mm];
                    f32x2 a_i = {acc[0][r0], acc[0][r0 + 1]};
                    f32x2 a_f = {acc[1][r0], acc[1][r0 + 1]};
                    f32x2 a_g = {acc[2][r0], acc[2][r0 + 1]};
                    f32x2 a_o = {acc[3][r0], acc[3][r0 + 1]};

                    // scaled gates -> exp2 directly (native vector math)
                    f32x2 ei = exp2v(a_i + xv2 * wihS[0]);
                    f32x2 ef = exp2v(a_f + xv2 * wihS[1]);
                    f32x2 eg = exp2v(a_g + xv2 * wihS[2]);
                    f32x2 eo = exp2v(a_o + xv2 * wihS[3]);

                    f32x2 di = ei + 1.0f;
                    f32x2 df = ef + 1.0f;
                    f32x2 dg = eg + 1.0f;
                    f32x2 dd = eo + 1.0f;

                    // batched reciprocal: 1 rcp per cell for 4 denominators
                    f32x2 t1 = di * df;
                    f32x2 t2 = dd * dg;
                    f32x2 P  = t1 * t2;
                    f32x2 R; R.x = frcp(P.x); R.y = frcp(P.y);
                    f32x2 R12 = R * t2;
                    f32x2 R34 = R * t1;
                    f32x2 si  = R12 * df;            // sigmoid(i)
                    f32x2 sf  = R12 * di;            // sigmoid(f)
                    f32x2 so  = R34 * dg;            // sigmoid(o)
                    f32x2 ig  = R34 * dd;            // 1/(1+e^{2g})
                    f32x2 tg  = 1.0f - 2.0f * ig;    // tanh(g)

                    f32x2 cp = c2[mt * 2 + pr];
                    f32x2 cn = si * tg + sf * cp;
                    f32x2 cf;
                    cf.x = m0 ? cn.x : cp.x;
                    cf.y = m1 ? cn.y : cp.y;
                    c2[mt * 2 + pr] = cf;

                    // tanh(c) with pair-batched rcp
                    f32x2 ec = exp2v(cf * (2.0f * LOG2E));
                    f32x2 dc = ec + 1.0f;
                    float Pc = dc.x * dc.y;
                    float Rc = frcp(Pc);
                    f32x2 invc; invc.x = Rc * dc.y; invc.y = Rc * dc.x;
                    f32x2 tc = 1.0f - 2.0f * invc;
                    f32x2 hn = so * tc;

                    const int hidx0 = (mm << 6)       + (((uhi ^ mm) & 7) << 3)       + ulo;
                    const int hidx1 = ((mm + 1) << 6) + (((uhi ^ (mm + 1)) & 7) << 3) + ulo;
                    float h0 = m0 ? hn.x : bf2f(rb[hidx0]);
                    float h1 = m1 ? hn.y : bf2f(rb[hidx1]);
                    wb[hidx0] = f2bf(h0);   // RNE — required
                    wb[hidx1] = f2bf(h1);
                }
            }
            __syncthreads();   // wb complete before it becomes next step's rb
        }
    }

    __builtin_amdgcn_sched_barrier(0);

    // ---- FC epilogue as MFMA: D[64s x 32f] = [Hf|Hb][64x128] @ Wfc^T ----
    {
        const short* Hf = Hbuf[0];
        const short* Hb = Hbuf[2];

        bf16x8 wfr[2][4];
        float  bias[2];
        #pragma unroll
        for (int nt = 0; nt < 2; nt++) {
            const int f = nt * 16 + n0;
            bias[nt] = bfc[f];
            #pragma unroll
            for (int kc = 0; kc < 4; kc++) {
                const float* src = Wfc + (size_t)f * 128 + kc * 32 + kq * 8;
                bf16x8 v;
                #pragma unroll
                for (int j = 0; j < 8; j++) v[j] = f2bf(src[j]);
                wfr[nt][kc] = v;
            }
        }

        const int ma = w * 16 + n0;
        const int sa = ma & 7;
        bf16x8 afr[4];
        #pragma unroll
        for (int kc = 0; kc < 2; kc++) {
            afr[kc]     = *(const bf16x8*)&Hf[ma * 64 + (((kc * 4 + kq) ^ sa) << 3)];
            afr[kc + 2] = *(const bf16x8*)&Hb[ma * 64 + (((kc * 4 + kq) ^ sa) << 3)];
        }

        f32x4 acc[2];
        #pragma unroll
        for (int nt = 0; nt < 2; nt++) {
            f32x4 z = {0.0f, 0.0f, 0.0f, 0.0f};
            acc[nt] = z;
            #pragma unroll
            for (int kc = 0; kc < 4; kc++)
                acc[nt] = __builtin_amdgcn_mfma_f32_16x16x32_bf16(afr[kc], wfr[nt][kc], acc[nt], 0, 0, 0);
        }

        #pragma unroll
        for (int nt = 0; nt < 2; nt++) {
            #pragma unroll
            for (int r = 0; r < 4; r++) {
                const int s   = w * 16 + kq * 4 + r;
                const int gs  = s0base + s;
                const int row = gs / NROI, rr = gs - row * NROI;
                float v = acc[nt][r] + bias[nt];
                combined[(size_t)row * COMB + rr * FCD + nt * 16 + n0] = v > 0.0f ? v : 0.0f;
            }
        }
    }
}

// ---------------------------------------------------------------------------
// Output projection: q[row][j] = b_out[j] + combined[row] . W_out[j]
// ---------------------------------------------------------------------------
__global__ __launch_bounds__(256) void qout_kernel(
    const float* __restrict__ combined,
    const float* __restrict__ Wout,
    const float* __restrict__ bout,
    float* __restrict__ q)
{
    const int j   = threadIdx.x;              // 0..31 (31 masked)
    const int r   = threadIdx.y;              // 0..7
    const int row = blockIdx.x * 8 + r;
    if (j >= ACTD) return;
    const float4* crow = (const float4*)(combined + (size_t)row * COMB);
    const float4* wrow = (const float4*)(Wout + (size_t)j * COMB);
    float acc = bout[j];
    #pragma unroll 4
    for (int k4 = 0; k4 < COMB / 4; k4++) {
        float4 c4 = crow[k4];
        float4 w4 = wrow[k4];
        acc += c4.x * w4.x + c4.y * w4.y + c4.z * w4.z + c4.w * w4.w;
    }
    q[(size_t)row * ACTD + j] = acc;
}

// ---------------------------------------------------------------------------
extern "C" void kernel_launch(void* const* d_in, const int* in_sizes, int n_in,
                              void* d_out, int out_size, void* d_ws, size_t ws_size,
                              hipStream_t stream)
{
    (void)in_sizes; (void)n_in; (void)out_size;
    const float* x     = (const float*)d_in[0];
    const float* Wih_f = (const float*)d_in[1];
    const float* Whh_f = (const float*)d_in[2];
    const float* bih_f = (const float*)d_in[3];
    const float* bhh_f = (const float*)d_in[4];
    const float* Wih_b = (const float*)d_in[5];
    const float* Whh_b = (const float*)d_in[6];
    const float* bih_b = (const float*)d_in[7];
    const float* bhh_b = (const float*)d_in[8];
    const float* Wfc   = (const float*)d_in[9];
    const float* bfc   = (const float*)d_in[10];
    const float* W1    = (const float*)d_in[11];
    const float* b1    = (const float*)d_in[12];
    const float* W2    = (const float*)d_in[13];
    const float* b2    = (const float*)d_in[14];
    const float* W3    = (const float*)d_in[15];
    const float* b3    = (const float*)d_in[16];
    const float* Wout  = (const float*)d_in[17];
    const float* bout  = (const float*)d_in[18];
    float* q        = (float*)d_out;
    float* combined = (float*)d_ws;   // 16384 x 1216 f32 = 79.7 MB

    if (ws_size < (size_t)NB * COMB * sizeof(float)) return;

    mlp_kernel<NOTHER><<<NB / 64, 256, 0, stream>>>(x + NROIF, NTOT, W1, b1, combined, COMB);
    mlp_kernel<NHD><<<NB / 64, 256, 0, stream>>>(combined, COMB, W2, b2, combined + 256, COMB);
    mlp_kernel<NHD><<<NB / 64, 256, 0, stream>>>(combined + 256, COMB, W3, b3, combined + 960, COMB);

    lstm_fc_mfma<<<NSEQ / 64, 256, 0, stream>>>(x, Wih_f, Whh_f, bih_f, bhh_f,
                                                Wih_b, Whh_b, bih_b, bhh_b,
                                                Wfc, bfc, combined);

    qout_kernel<<<NB / 8, dim3(32, 8), 0, stream>>>(combined, Wout, bout, q);
}